// Round 1
// baseline (2085.527 us; speedup 1.0000x reference)
//
#include <hip/hip_runtime.h>

#define NLAT 721
#define NLON 1440
#define NB 4
#define ND 5
#define NROWS (NLAT*ND)          // 3605
#define PLANE (NLAT*NLON)        // 1,038,240
#define HVOL (NB*PLANE)          // 4,152,960
#define DTSTEP 0.01f

// ---------------------------------------------------------------------------
// Kernel A: per (lat,d) row, find the wrapped-interval support [jlo, jhi]
// (signed lon offsets, j in [-720, 719]) where any of the 4 kernels != 0.
// ---------------------------------------------------------------------------
__global__ __launch_bounds__(64) void support_kernel(
    const float* __restrict__ Kgc, const float* __restrict__ Kgs,
    const float* __restrict__ Kdc, const float* __restrict__ Kds,
    int* __restrict__ jlo_a, int* __restrict__ cnt_a)
{
  int row = blockIdx.x;
  int lane = threadIdx.x;
  const float* a = Kgc + (size_t)row * NLON;
  const float* b = Kgs + (size_t)row * NLON;
  const float* c = Kdc + (size_t)row * NLON;
  const float* d = Kds + (size_t)row * NLON;
  int jmin = 1 << 30, jmax = -(1 << 30);
  for (int m = lane; m < NLON; m += 64) {
    float s = fabsf(a[m]) + fabsf(b[m]) + fabsf(c[m]) + fabsf(d[m]);
    if (s != 0.0f) {
      int j = (m >= NLON / 2) ? (m - NLON) : m;
      jmin = min(jmin, j);
      jmax = max(jmax, j);
    }
  }
  for (int s = 32; s > 0; s >>= 1) {
    jmin = min(jmin, __shfl_down(jmin, s));
    jmax = max(jmax, __shfl_down(jmax, s));
  }
  if (lane == 0) {
    if (jmax < jmin) { jlo_a[row] = 0; cnt_a[row] = 0; }
    else             { jlo_a[row] = jmin; cnt_a[row] = jmax - jmin + 1; }
  }
}

// ---------------------------------------------------------------------------
// Kernel B: exclusive prefix sum over the 3605 row counts (single block),
// then per-latitude [offset, count] (d-rows of one lat are contiguous).
// ---------------------------------------------------------------------------
__global__ __launch_bounds__(256) void scan_kernel(
    const int* __restrict__ cnt_a, int* __restrict__ off_a,
    int* __restrict__ latoff, int* __restrict__ latcnt, int tap_cap)
{
  __shared__ int buf[256];
  __shared__ int carry;
  int tid = threadIdx.x;
  if (tid == 0) carry = 0;
  __syncthreads();
  for (int base = 0; base < NROWS; base += 256) {
    int i = base + tid;
    int v = (i < NROWS) ? cnt_a[i] : 0;
    buf[tid] = v;
    __syncthreads();
    for (int s = 1; s < 256; s <<= 1) {
      int t = (tid >= s) ? buf[tid - s] : 0;
      __syncthreads();
      buf[tid] += t;
      __syncthreads();
    }
    if (i < NROWS) off_a[i] = carry + buf[tid] - v;   // exclusive
    __syncthreads();
    if (tid == 255) carry += buf[255];
    __syncthreads();
  }
  for (int l = tid; l < NLAT; l += 256) {
    int s0 = off_a[5 * l];
    int e  = off_a[5 * l + 4] + cnt_a[5 * l + 4];
    int c  = e - s0;
    if (s0 >= tap_cap)          c = 0;
    else if (s0 + c > tap_cap)  c = tap_cap - s0;
    latoff[l] = s0;
    latcnt[l] = c;
  }
}

// ---------------------------------------------------------------------------
// Kernel C: fill packed tap pool.
// tapw = (Kg_c, Kg_s, Kd_c, Kd_s), tapm = (src_row << 16) | (j + 720)
// ---------------------------------------------------------------------------
__global__ __launch_bounds__(64) void fill_kernel(
    const float* __restrict__ Kgc, const float* __restrict__ Kgs,
    const float* __restrict__ Kdc, const float* __restrict__ Kds,
    const int* __restrict__ jlo_a, const int* __restrict__ cnt_a,
    const int* __restrict__ off_a,
    float4* __restrict__ tapw, int* __restrict__ tapm, int tap_cap)
{
  int row = blockIdx.x;
  int l = row / ND, d = row % ND;
  int jlo = jlo_a[row], cnt = cnt_a[row], off = off_a[row];
  int iq = min(max(l + d - 2, 0), NLAT - 1);
  for (int t = threadIdx.x; t < cnt; t += 64) {
    int p = off + t;
    if (p >= tap_cap) break;
    int j = jlo + t;
    int m = j + ((j < 0) ? NLON : 0);
    size_t idx = (size_t)row * NLON + m;
    tapw[p] = make_float4(Kgc[idx], Kgs[idx], Kdc[idx], Kds[idx]);
    tapm[p] = (iq << 16) | (j + 720);
  }
}

// ---------------------------------------------------------------------------
// Stage kernel: tendency (sparse correlation + Coriolis) fused with RK4
// state update (Xnext = S0 + cdt*k) and accumulator update (acc += wacc*k).
// Final stage writes out = S0 + DT/6*(acc + k4) in-place in d_out.
// Grid: (23 lon-chunks of 64, NLAT, NB); block: 256 = 4 waves.
// Waves split the tap list 4-way (polar rows have ~1500 taps) -> LDS reduce.
// ---------------------------------------------------------------------------
__global__ __launch_bounds__(256) void stage_kernel(
    const float* __restrict__ Xh, const float* __restrict__ Xuv,
    const float* __restrict__ S0h, const float* __restrict__ S0uv,
    const float* __restrict__ fcor,
    const int* __restrict__ latoff, const int* __restrict__ latcnt,
    const float4* __restrict__ tapw, const int* __restrict__ tapm,
    float* __restrict__ Xn_h, float* __restrict__ Xn_uv,
    float* __restrict__ acc_h, float* __restrict__ acc_uv,
    float cdt, float wacc, int is_final)
{
  int chunk = blockIdx.x;          // 0..22, 64 lons each (last partial)
  int l = blockIdx.y;
  int b = blockIdx.z;
  int wave = threadIdx.x >> 6;
  int lane = threadIdx.x & 63;
  int n = chunk * 64 + lane;
  bool act = n < NLON;

  int t0 = latoff[l];
  int cnt = latcnt[l];
  int mycnt = act ? cnt : 0;       // inactive lanes must not load (OOB)

  const float* __restrict__ xh  = Xh  + (size_t)b * PLANE;
  const float* __restrict__ xuv = Xuv + (size_t)b * PLANE * 2;

  float ah = 0.f, au = 0.f, av = 0.f;
  for (int t = wave; t < mycnt; t += 4) {
    int   meta = tapm[t0 + t];
    float4 w   = tapw[t0 + t];
    int j  = (meta & 0xffff) - 720;
    int iq = meta >> 16;
    int nn = n + j;
    nn += (nn < 0) ? NLON : 0;
    nn -= (nn >= NLON) ? NLON : 0;
    int src = iq * NLON + nn;
    float  hh = xh[src];
    float2 uv = *(const float2*)(xuv + 2 * (size_t)src);
    ah += w.z * uv.x + w.w * uv.y;   // Kd_c*u + Kd_s*v
    au += w.x * hh;                  // Kg_c*h
    av += w.y * hh;                  // Kg_s*h
  }

  __shared__ float red[4][3][64];
  red[wave][0][lane] = ah;
  red[wave][1][lane] = au;
  red[wave][2][lane] = av;
  __syncthreads();

  if (wave == 0 && act) {
    ah = red[0][0][lane] + red[1][0][lane] + red[2][0][lane] + red[3][0][lane];
    au = red[0][1][lane] + red[1][1][lane] + red[2][1][lane] + red[3][1][lane];
    av = red[0][2][lane] + red[1][2][lane] + red[2][2][lane] + red[3][2][lane];
    float f = fcor[l];
    float2 uvc = *(const float2*)(xuv + 2 * ((size_t)l * NLON + n));
    float kh = -ah;                  // dh = -H0 * (corr)
    float ku = -au - f * uvc.y;      // du - f*v
    float kv = -av + f * uvc.x;      // dv + f*u
    size_t ih  = (size_t)b * PLANE + (size_t)l * NLON + n;
    size_t iuv = ih * 2;
    if (!is_final) {
      Xn_h[ih] = S0h[ih] + cdt * kh;
      float2 s0 = *(const float2*)(S0uv + iuv);
      float2 xo;
      xo.x = s0.x + cdt * ku;
      xo.y = s0.y + cdt * kv;
      *(float2*)(Xn_uv + iuv) = xo;
      acc_h[ih] += wacc * kh;
      float2 a0 = *(const float2*)(acc_uv + iuv);
      a0.x += wacc * ku;
      a0.y += wacc * kv;
      *(float2*)(acc_uv + iuv) = a0;
    } else {
      const float DT6 = DTSTEP / 6.0f;
      acc_h[ih] = S0h[ih] + DT6 * (acc_h[ih] + kh);
      float2 s0 = *(const float2*)(S0uv + iuv);
      float2 a0 = *(const float2*)(acc_uv + iuv);
      a0.x = s0.x + DT6 * (a0.x + ku);
      a0.y = s0.y + DT6 * (a0.y + kv);
      *(float2*)(acc_uv + iuv) = a0;
    }
  }
}

// ---------------------------------------------------------------------------
extern "C" void kernel_launch(void* const* d_in, const int* in_sizes, int n_in,
                              void* d_out, int out_size, void* d_ws, size_t ws_size,
                              hipStream_t stream)
{
  const float* h0   = (const float*)d_in[0];
  const float* uv0  = (const float*)d_in[1];
  const float* Kgc  = (const float*)d_in[2];
  const float* Kgs  = (const float*)d_in[3];
  const float* Kdc  = (const float*)d_in[4];
  const float* Kds  = (const float*)d_in[5];
  const float* fcor = (const float*)d_in[6];

  char* ws = (char*)d_ws;
  size_t pos = 0;
  auto carve = [&](size_t bytes) -> void* {
    void* p = ws + pos;
    pos += (bytes + 255) & ~(size_t)255;
    return p;
  };

  int*   jlo_a  = (int*)carve(sizeof(int) * NROWS);
  int*   cnt_a  = (int*)carve(sizeof(int) * NROWS);
  int*   off_a  = (int*)carve(sizeof(int) * NROWS);
  int*   latoff = (int*)carve(sizeof(int) * NLAT);
  int*   latcnt = (int*)carve(sizeof(int) * NLAT);
  float* Xa     = (float*)carve(sizeof(float) * 3 * (size_t)HVOL);
  float* Xb     = (float*)carve(sizeof(float) * 3 * (size_t)HVOL);

  // Remaining workspace -> tap pool (16B weights + 4B meta per tap).
  size_t remain = (ws_size > pos + 512) ? (ws_size - pos - 512) : 0;
  long long cap_ll = (long long)(remain / 20);
  if (cap_ll > (1 << 22)) cap_ll = (1 << 22);   // 4M taps is >>80x expected
  int tap_cap = (int)cap_ll;
  float4* tapw = (float4*)carve(sizeof(float4) * (size_t)tap_cap);
  int*    tapm = (int*)carve(sizeof(int) * (size_t)tap_cap);

  float* Xa_h = Xa;  float* Xa_uv = Xa + HVOL;
  float* Xb_h = Xb;  float* Xb_uv = Xb + HVOL;
  float* acc_h  = (float*)d_out;          // [NB,1,NLAT,NLON]
  float* acc_uv = (float*)d_out + HVOL;   // [NB,1,NLAT,NLON,2]

  hipMemsetAsync(d_out, 0, sizeof(float) * (size_t)out_size, stream);

  support_kernel<<<NROWS, 64, 0, stream>>>(Kgc, Kgs, Kdc, Kds, jlo_a, cnt_a);
  scan_kernel<<<1, 256, 0, stream>>>(cnt_a, off_a, latoff, latcnt, tap_cap);
  fill_kernel<<<NROWS, 64, 0, stream>>>(Kgc, Kgs, Kdc, Kds, jlo_a, cnt_a, off_a,
                                        tapw, tapm, tap_cap);

  dim3 grid(23, NLAT, NB);
  // k1: X = S0
  stage_kernel<<<grid, 256, 0, stream>>>(h0, uv0, h0, uv0, fcor, latoff, latcnt,
                                         tapw, tapm, Xa_h, Xa_uv, acc_h, acc_uv,
                                         0.5f * DTSTEP, 1.0f, 0);
  // k2: X = S0 + dt/2 k1
  stage_kernel<<<grid, 256, 0, stream>>>(Xa_h, Xa_uv, h0, uv0, fcor, latoff, latcnt,
                                         tapw, tapm, Xb_h, Xb_uv, acc_h, acc_uv,
                                         0.5f * DTSTEP, 2.0f, 0);
  // k3: X = S0 + dt/2 k2
  stage_kernel<<<grid, 256, 0, stream>>>(Xb_h, Xb_uv, h0, uv0, fcor, latoff, latcnt,
                                         tapw, tapm, Xa_h, Xa_uv, acc_h, acc_uv,
                                         DTSTEP, 2.0f, 0);
  // k4: X = S0 + dt k3 ; final: out = S0 + dt/6*(acc + k4)
  stage_kernel<<<grid, 256, 0, stream>>>(Xa_h, Xa_uv, h0, uv0, fcor, latoff, latcnt,
                                         tapw, tapm, Xb_h, Xb_uv, acc_h, acc_uv,
                                         0.0f, 0.0f, 1);
}

// Round 2
// 1281.467 us; speedup vs baseline: 1.6275x; 1.6275x over previous
//
#include <hip/hip_runtime.h>

#define NLAT 721
#define NLON 1440
#define NB 4
#define ND 5
#define NROWS (NLAT*ND)          // 3605
#define PLANE (NLAT*NLON)        // 1,038,240
#define HVOL (NB*PLANE)          // 4,152,960
#define DTSTEP 0.01f
#define SPLIT 512                // lat is "big" if cnt > SPLIT
#define TCH 256                  // taps per big work item
#define NWORK_CAP 4096
#define NYSLOT 64                // big-kernel work slots

// ---------------------------------------------------------------------------
// Kernel A: per (lat,d) row, find the wrapped-interval support [jlo, jhi]
// ---------------------------------------------------------------------------
__global__ __launch_bounds__(64) void support_kernel(
    const float* __restrict__ Kgc, const float* __restrict__ Kgs,
    const float* __restrict__ Kdc, const float* __restrict__ Kds,
    int* __restrict__ jlo_a, int* __restrict__ cnt_a)
{
  int row = blockIdx.x;
  int lane = threadIdx.x;
  const float* a = Kgc + (size_t)row * NLON;
  const float* b = Kgs + (size_t)row * NLON;
  const float* c = Kdc + (size_t)row * NLON;
  const float* d = Kds + (size_t)row * NLON;
  int jmin = 1 << 30, jmax = -(1 << 30);
  for (int m = lane; m < NLON; m += 64) {
    float s = fabsf(a[m]) + fabsf(b[m]) + fabsf(c[m]) + fabsf(d[m]);
    if (s != 0.0f) {
      int j = (m >= NLON / 2) ? (m - NLON) : m;
      jmin = min(jmin, j);
      jmax = max(jmax, j);
    }
  }
  for (int s = 32; s > 0; s >>= 1) {
    jmin = min(jmin, __shfl_down(jmin, s));
    jmax = max(jmax, __shfl_down(jmax, s));
  }
  if (lane == 0) {
    if (jmax < jmin) { jlo_a[row] = 0; cnt_a[row] = 0; }
    else             { jlo_a[row] = jmin; cnt_a[row] = jmax - jmin + 1; }
  }
}

// ---------------------------------------------------------------------------
// Kernel B: prefix sum over row counts; per-lat [offset,count]; big-lat
// worklist of (lat, tap-chunk) items.
// ---------------------------------------------------------------------------
__global__ __launch_bounds__(256) void scan_kernel(
    const int* __restrict__ cnt_a, int* __restrict__ off_a,
    int* __restrict__ latoff, int* __restrict__ latcnt,
    int2* __restrict__ work, int* __restrict__ nbig, int tap_cap)
{
  __shared__ int buf[256];
  __shared__ int carry;
  int tid = threadIdx.x;
  if (tid == 0) carry = 0;
  __syncthreads();
  for (int base = 0; base < NROWS; base += 256) {
    int i = base + tid;
    int v = (i < NROWS) ? cnt_a[i] : 0;
    buf[tid] = v;
    __syncthreads();
    for (int s = 1; s < 256; s <<= 1) {
      int t = (tid >= s) ? buf[tid - s] : 0;
      __syncthreads();
      buf[tid] += t;
      __syncthreads();
    }
    if (i < NROWS) off_a[i] = carry + buf[tid] - v;   // exclusive
    __syncthreads();
    if (tid == 255) carry += buf[255];
    __syncthreads();
  }
  for (int l = tid; l < NLAT; l += 256) {
    int s0 = off_a[5 * l];
    int e  = off_a[5 * l + 4] + cnt_a[5 * l + 4];
    int c  = e - s0;
    if (s0 >= tap_cap)          c = 0;
    else if (s0 + c > tap_cap)  c = tap_cap - s0;
    latoff[l] = s0;
    latcnt[l] = c;
  }
  __syncthreads();
  if (tid == 0) {
    int nw = 0;
    for (int l = 0; l < NLAT; ++l) {
      int c = latcnt[l];
      if (c > SPLIT) {
        int nch = (c + TCH - 1) / TCH;
        for (int k = 0; k < nch && nw < NWORK_CAP; ++k)
          work[nw++] = make_int2(l, k);
      }
    }
    *nbig = nw;
  }
}

// ---------------------------------------------------------------------------
// Kernel C: fill packed tap pool.
// tapw = (Kg_c, Kg_s, Kd_c, Kd_s), tapm = (src_row << 16) | (j + 720)
// ---------------------------------------------------------------------------
__global__ __launch_bounds__(64) void fill_kernel(
    const float* __restrict__ Kgc, const float* __restrict__ Kgs,
    const float* __restrict__ Kdc, const float* __restrict__ Kds,
    const int* __restrict__ jlo_a, const int* __restrict__ cnt_a,
    const int* __restrict__ off_a,
    float4* __restrict__ tapw, int* __restrict__ tapm, int tap_cap)
{
  int row = blockIdx.x;
  int l = row / ND, d = row % ND;
  int jlo = jlo_a[row], cnt = cnt_a[row], off = off_a[row];
  int iq = min(max(l + d - 2, 0), NLAT - 1);
  for (int t = threadIdx.x; t < cnt; t += 64) {
    int p = off + t;
    if (p >= tap_cap) break;
    int j = jlo + t;
    int m = j + ((j < 0) ? NLON : 0);
    size_t idx = (size_t)row * NLON + m;
    tapw[p] = make_float4(Kgc[idx], Kgs[idx], Kdc[idx], Kds[idx]);
    tapm[p] = (iq << 16) | (j + 720);
  }
}

// ---------------------------------------------------------------------------
// Zero k-scratch rows of big lats only.  Grid (NLAT, NB), block 256.
// ---------------------------------------------------------------------------
__global__ __launch_bounds__(256) void zero_kernel(
    const int* __restrict__ latcnt,
    float* __restrict__ kh, float* __restrict__ kuv)
{
  int l = blockIdx.x, b = blockIdx.y;
  if (latcnt[l] <= SPLIT) return;
  size_t base = (size_t)b * PLANE + (size_t)l * NLON;
  for (int i = threadIdx.x; i < NLON; i += 256) kh[base + i] = 0.f;
  for (int i = threadIdx.x; i < 2 * NLON; i += 256) kuv[2 * base + i] = 0.f;
}

// ---------------------------------------------------------------------------
// Big-lat correlation: fixed balanced grid (23, NYSLOT, NB), block 256.
// Strides over worklist items (lat, tap-chunk); stages TCH taps in LDS;
// atomicAdd raw correlation partials into k-scratch.
// ---------------------------------------------------------------------------
__global__ __launch_bounds__(256) void big_kernel(
    const float* __restrict__ Xh, const float* __restrict__ Xuv,
    const int* __restrict__ latoff, const int* __restrict__ latcnt,
    const float4* __restrict__ tapw, const int* __restrict__ tapm,
    const int2* __restrict__ work, const int* __restrict__ nbig,
    float* __restrict__ kh, float* __restrict__ kuv)
{
  __shared__ float4 sw[TCH];
  __shared__ int    sm[TCH];
  __shared__ float  red[4][3][64];

  int nbw = *nbig;
  int chunk = blockIdx.x;
  int b = blockIdx.z;
  int tid = threadIdx.x;
  int wave = tid >> 6;
  int lane = tid & 63;
  int n = chunk * 64 + lane;
  bool act = n < NLON;

  const float* __restrict__ xh  = Xh  + (size_t)b * PLANE;
  const float* __restrict__ xuv = Xuv + (size_t)b * PLANE * 2;

  for (int w = blockIdx.y; w < nbw; w += NYSLOT) {
    int2 it = work[w];
    int l = it.x;
    int t0 = latoff[l] + it.y * TCH;
    int tcnt = min(TCH, latcnt[l] - it.y * TCH);

    __syncthreads();                      // protect sw/sm + red reuse
    if (tid < tcnt) { sw[tid] = tapw[t0 + tid]; sm[tid] = tapm[t0 + tid]; }
    __syncthreads();

    float ah = 0.f, au = 0.f, av = 0.f;
    int mycnt = act ? tcnt : 0;
    #pragma unroll 4
    for (int t = wave; t < mycnt; t += 4) {
      int   meta = sm[t];
      float4 wv  = sw[t];
      int j  = (meta & 0xffff) - 720;
      int iq = meta >> 16;
      int nn = n + j;
      nn += (nn < 0) ? NLON : 0;
      nn -= (nn >= NLON) ? NLON : 0;
      int src = iq * NLON + nn;
      float  hh = xh[src];
      float2 uv = *(const float2*)(xuv + 2 * (size_t)src);
      ah += wv.z * uv.x + wv.w * uv.y;
      au += wv.x * hh;
      av += wv.y * hh;
    }

    red[wave][0][lane] = ah;
    red[wave][1][lane] = au;
    red[wave][2][lane] = av;
    __syncthreads();

    if (wave == 0 && act) {
      ah = red[0][0][lane] + red[1][0][lane] + red[2][0][lane] + red[3][0][lane];
      au = red[0][1][lane] + red[1][1][lane] + red[2][1][lane] + red[3][1][lane];
      av = red[0][2][lane] + red[1][2][lane] + red[2][2][lane] + red[3][2][lane];
      size_t ih = (size_t)b * PLANE + (size_t)l * NLON + n;
      atomicAdd(&kh[ih], ah);
      atomicAdd(&kuv[2 * ih],     au);
      atomicAdd(&kuv[2 * ih + 1], av);
    }
  }
}

// ---------------------------------------------------------------------------
// Fused stage kernel: small lats compute corr from LDS-staged taps; big lats
// read k-scratch.  Wave 0 applies Coriolis + RK4 update + accumulator.
// Grid: (23, NLAT, NB), block 256.
// ---------------------------------------------------------------------------
__global__ __launch_bounds__(256) void stage_kernel(
    const float* __restrict__ Xh, const float* __restrict__ Xuv,
    const float* __restrict__ S0h, const float* __restrict__ S0uv,
    const float* __restrict__ fcor,
    const int* __restrict__ latoff, const int* __restrict__ latcnt,
    const float4* __restrict__ tapw, const int* __restrict__ tapm,
    const float* __restrict__ kh_s, const float* __restrict__ kuv_s,
    float* __restrict__ Xn_h, float* __restrict__ Xn_uv,
    float* __restrict__ acc_h, float* __restrict__ acc_uv,
    float cdt, float wacc, int is_final)
{
  __shared__ float4 sw[SPLIT];
  __shared__ int    sm[SPLIT];
  __shared__ float  red[4][3][64];

  int chunk = blockIdx.x;
  int l = blockIdx.y;
  int b = blockIdx.z;
  int tid = threadIdx.x;
  int wave = tid >> 6;
  int lane = tid & 63;
  int n = chunk * 64 + lane;
  bool act = n < NLON;

  int cnt = latcnt[l];
  int t0 = latoff[l];

  const float* __restrict__ xh  = Xh  + (size_t)b * PLANE;
  const float* __restrict__ xuv = Xuv + (size_t)b * PLANE * 2;

  float ah = 0.f, au = 0.f, av = 0.f;

  if (cnt <= SPLIT) {                      // block-uniform branch
    for (int t = tid; t < cnt; t += 256) { sw[t] = tapw[t0 + t]; sm[t] = tapm[t0 + t]; }
    __syncthreads();

    int mycnt = act ? cnt : 0;
    #pragma unroll 4
    for (int t = wave; t < mycnt; t += 4) {
      int   meta = sm[t];
      float4 wv  = sw[t];
      int j  = (meta & 0xffff) - 720;
      int iq = meta >> 16;
      int nn = n + j;
      nn += (nn < 0) ? NLON : 0;
      nn -= (nn >= NLON) ? NLON : 0;
      int src = iq * NLON + nn;
      float  hh = xh[src];
      float2 uv = *(const float2*)(xuv + 2 * (size_t)src);
      ah += wv.z * uv.x + wv.w * uv.y;
      au += wv.x * hh;
      av += wv.y * hh;
    }

    red[wave][0][lane] = ah;
    red[wave][1][lane] = au;
    red[wave][2][lane] = av;
    __syncthreads();

    if (wave == 0 && act) {
      ah = red[0][0][lane] + red[1][0][lane] + red[2][0][lane] + red[3][0][lane];
      au = red[0][1][lane] + red[1][1][lane] + red[2][1][lane] + red[3][1][lane];
      av = red[0][2][lane] + red[1][2][lane] + red[2][2][lane] + red[3][2][lane];
    }
  } else {
    if (wave == 0 && act) {
      size_t ih = (size_t)b * PLANE + (size_t)l * NLON + n;
      ah = kh_s[ih];
      float2 kuv2 = *(const float2*)(kuv_s + 2 * ih);
      au = kuv2.x;
      av = kuv2.y;
    }
  }

  if (wave == 0 && act) {
    float f = fcor[l];
    float2 uvc = *(const float2*)(xuv + 2 * ((size_t)l * NLON + n));
    float kh = -ah;                  // dh = -H0 * corr
    float ku = -au - f * uvc.y;      // du - f*v
    float kv = -av + f * uvc.x;      // dv + f*u
    size_t ih  = (size_t)b * PLANE + (size_t)l * NLON + n;
    size_t iuv = ih * 2;
    if (!is_final) {
      Xn_h[ih] = S0h[ih] + cdt * kh;
      float2 s0 = *(const float2*)(S0uv + iuv);
      float2 xo;
      xo.x = s0.x + cdt * ku;
      xo.y = s0.y + cdt * kv;
      *(float2*)(Xn_uv + iuv) = xo;
      acc_h[ih] += wacc * kh;
      float2 a0 = *(const float2*)(acc_uv + iuv);
      a0.x += wacc * ku;
      a0.y += wacc * kv;
      *(float2*)(acc_uv + iuv) = a0;
    } else {
      const float DT6 = DTSTEP / 6.0f;
      acc_h[ih] = S0h[ih] + DT6 * (acc_h[ih] + kh);
      float2 s0 = *(const float2*)(S0uv + iuv);
      float2 a0 = *(const float2*)(acc_uv + iuv);
      a0.x = s0.x + DT6 * (a0.x + ku);
      a0.y = s0.y + DT6 * (a0.y + kv);
      *(float2*)(acc_uv + iuv) = a0;
    }
  }
}

// ---------------------------------------------------------------------------
extern "C" void kernel_launch(void* const* d_in, const int* in_sizes, int n_in,
                              void* d_out, int out_size, void* d_ws, size_t ws_size,
                              hipStream_t stream)
{
  const float* h0   = (const float*)d_in[0];
  const float* uv0  = (const float*)d_in[1];
  const float* Kgc  = (const float*)d_in[2];
  const float* Kgs  = (const float*)d_in[3];
  const float* Kdc  = (const float*)d_in[4];
  const float* Kds  = (const float*)d_in[5];
  const float* fcor = (const float*)d_in[6];

  char* ws = (char*)d_ws;
  size_t pos = 0;
  auto carve = [&](size_t bytes) -> void* {
    void* p = ws + pos;
    pos += (bytes + 255) & ~(size_t)255;
    return p;
  };

  int*   jlo_a  = (int*)carve(sizeof(int) * NROWS);
  int*   cnt_a  = (int*)carve(sizeof(int) * NROWS);
  int*   off_a  = (int*)carve(sizeof(int) * NROWS);
  int*   latoff = (int*)carve(sizeof(int) * NLAT);
  int*   latcnt = (int*)carve(sizeof(int) * NLAT);
  int2*  work   = (int2*)carve(sizeof(int2) * NWORK_CAP);
  int*   nbig   = (int*)carve(sizeof(int));
  float* Xa     = (float*)carve(sizeof(float) * 3 * (size_t)HVOL);
  float* Xb     = (float*)carve(sizeof(float) * 3 * (size_t)HVOL);
  float* kh     = (float*)carve(sizeof(float) * (size_t)HVOL);
  float* kuv    = (float*)carve(sizeof(float) * 2 * (size_t)HVOL);

  int tap_cap = 262144;   // ~4x expected total tap count (~65k)
  float4* tapw = (float4*)carve(sizeof(float4) * (size_t)tap_cap);
  int*    tapm = (int*)carve(sizeof(int) * (size_t)tap_cap);

  float* Xa_h = Xa;  float* Xa_uv = Xa + HVOL;
  float* Xb_h = Xb;  float* Xb_uv = Xb + HVOL;
  float* acc_h  = (float*)d_out;          // [NB,1,NLAT,NLON]
  float* acc_uv = (float*)d_out + HVOL;   // [NB,1,NLAT,NLON,2]

  hipMemsetAsync(d_out, 0, sizeof(float) * (size_t)out_size, stream);

  support_kernel<<<NROWS, 64, 0, stream>>>(Kgc, Kgs, Kdc, Kds, jlo_a, cnt_a);
  scan_kernel<<<1, 256, 0, stream>>>(cnt_a, off_a, latoff, latcnt, work, nbig, tap_cap);
  fill_kernel<<<NROWS, 64, 0, stream>>>(Kgc, Kgs, Kdc, Kds, jlo_a, cnt_a, off_a,
                                        tapw, tapm, tap_cap);

  dim3 gz(NLAT, NB);
  dim3 gb(23, NYSLOT, NB);
  dim3 gs(23, NLAT, NB);

  struct Stage { const float *xh, *xuv; float *nh, *nuv; float cdt, wacc; int fin; };
  Stage st[4] = {
    { h0,   uv0,   Xa_h, Xa_uv, 0.5f * DTSTEP, 1.0f, 0 },
    { Xa_h, Xa_uv, Xb_h, Xb_uv, 0.5f * DTSTEP, 2.0f, 0 },
    { Xb_h, Xb_uv, Xa_h, Xa_uv, DTSTEP,        2.0f, 0 },
    { Xa_h, Xa_uv, Xb_h, Xb_uv, 0.0f,          0.0f, 1 },
  };

  for (int s = 0; s < 4; ++s) {
    zero_kernel<<<gz, 256, 0, stream>>>(latcnt, kh, kuv);
    big_kernel<<<gb, 256, 0, stream>>>(st[s].xh, st[s].xuv, latoff, latcnt,
                                       tapw, tapm, work, nbig, kh, kuv);
    stage_kernel<<<gs, 256, 0, stream>>>(st[s].xh, st[s].xuv, h0, uv0, fcor,
                                         latoff, latcnt, tapw, tapm, kh, kuv,
                                         st[s].nh, st[s].nuv, acc_h, acc_uv,
                                         st[s].cdt, st[s].wacc, st[s].fin);
  }
}

// Round 3
// 1141.890 us; speedup vs baseline: 1.8264x; 1.1222x over previous
//
#include <hip/hip_runtime.h>

#define NLAT 721
#define NLON 1440
#define NB 4
#define ND 5
#define NROWS (NLAT*ND)          // 3605
#define PLANE (NLAT*NLON)        // 1,038,240
#define HVOL (NB*PLANE)          // 4,152,960
#define DTSTEP 0.01f
#define SPLIT 512                // lat is "big" if cnt > SPLIT
#define TCH 256                  // taps per big work item
#define NWORK_CAP 4096
#define NYSLOT 64                // big-kernel work slots

// ---------------------------------------------------------------------------
// Kernel A: per (lat,d) row, find the wrapped-interval support [jlo, jhi]
// ---------------------------------------------------------------------------
__global__ __launch_bounds__(64) void support_kernel(
    const float* __restrict__ Kgc, const float* __restrict__ Kgs,
    const float* __restrict__ Kdc, const float* __restrict__ Kds,
    int* __restrict__ jlo_a, int* __restrict__ cnt_a)
{
  int row = blockIdx.x;
  int lane = threadIdx.x;
  const float* a = Kgc + (size_t)row * NLON;
  const float* b = Kgs + (size_t)row * NLON;
  const float* c = Kdc + (size_t)row * NLON;
  const float* d = Kds + (size_t)row * NLON;
  int jmin = 1 << 30, jmax = -(1 << 30);
  for (int m = lane; m < NLON; m += 64) {
    float s = fabsf(a[m]) + fabsf(b[m]) + fabsf(c[m]) + fabsf(d[m]);
    if (s != 0.0f) {
      int j = (m >= NLON / 2) ? (m - NLON) : m;
      jmin = min(jmin, j);
      jmax = max(jmax, j);
    }
  }
  for (int s = 32; s > 0; s >>= 1) {
    jmin = min(jmin, __shfl_down(jmin, s));
    jmax = max(jmax, __shfl_down(jmax, s));
  }
  if (lane == 0) {
    if (jmax < jmin) { jlo_a[row] = 0; cnt_a[row] = 0; }
    else             { jlo_a[row] = jmin; cnt_a[row] = jmax - jmin + 1; }
  }
}

// ---------------------------------------------------------------------------
// Kernel B: prefix sum over row counts; per-lat [offset,count]; big-lat
// worklist of (lat, tap-chunk) items.
// ---------------------------------------------------------------------------
__global__ __launch_bounds__(256) void scan_kernel(
    const int* __restrict__ cnt_a, int* __restrict__ off_a,
    int* __restrict__ latoff, int* __restrict__ latcnt,
    int2* __restrict__ work, int* __restrict__ nbig, int tap_cap)
{
  __shared__ int buf[256];
  __shared__ int carry;
  int tid = threadIdx.x;
  if (tid == 0) carry = 0;
  __syncthreads();
  for (int base = 0; base < NROWS; base += 256) {
    int i = base + tid;
    int v = (i < NROWS) ? cnt_a[i] : 0;
    buf[tid] = v;
    __syncthreads();
    for (int s = 1; s < 256; s <<= 1) {
      int t = (tid >= s) ? buf[tid - s] : 0;
      __syncthreads();
      buf[tid] += t;
      __syncthreads();
    }
    if (i < NROWS) off_a[i] = carry + buf[tid] - v;   // exclusive
    __syncthreads();
    if (tid == 255) carry += buf[255];
    __syncthreads();
  }
  for (int l = tid; l < NLAT; l += 256) {
    int s0 = off_a[5 * l];
    int e  = off_a[5 * l + 4] + cnt_a[5 * l + 4];
    int c  = e - s0;
    if (s0 >= tap_cap)          c = 0;
    else if (s0 + c > tap_cap)  c = tap_cap - s0;
    latoff[l] = s0;
    latcnt[l] = c;
  }
  __syncthreads();
  if (tid == 0) {
    int nw = 0;
    for (int l = 0; l < NLAT; ++l) {
      int c = latcnt[l];
      if (c > SPLIT) {
        int nch = (c + TCH - 1) / TCH;
        for (int k = 0; k < nch && nw < NWORK_CAP; ++k)
          work[nw++] = make_int2(l, k);
      }
    }
    *nbig = nw;
  }
}

// ---------------------------------------------------------------------------
// Kernel C: fill packed tap pool.
// tapw = (Kg_c, Kg_s, Kd_c, Kd_s), tapm = (iq*NLON, j)
// ---------------------------------------------------------------------------
__global__ __launch_bounds__(64) void fill_kernel(
    const float* __restrict__ Kgc, const float* __restrict__ Kgs,
    const float* __restrict__ Kdc, const float* __restrict__ Kds,
    const int* __restrict__ jlo_a, const int* __restrict__ cnt_a,
    const int* __restrict__ off_a,
    float4* __restrict__ tapw, int2* __restrict__ tapm, int tap_cap)
{
  int row = blockIdx.x;
  int l = row / ND, d = row % ND;
  int jlo = jlo_a[row], cnt = cnt_a[row], off = off_a[row];
  int iq = min(max(l + d - 2, 0), NLAT - 1);
  for (int t = threadIdx.x; t < cnt; t += 64) {
    int p = off + t;
    if (p >= tap_cap) break;
    int j = jlo + t;
    int m = j + ((j < 0) ? NLON : 0);
    size_t idx = (size_t)row * NLON + m;
    tapw[p] = make_float4(Kgc[idx], Kgs[idx], Kdc[idx], Kds[idx]);
    tapm[p] = make_int2(iq * NLON, j);
  }
}

// ---------------------------------------------------------------------------
// Zero k-scratch rows of big lats only.  Grid (NLAT, NB), block 256.
// ---------------------------------------------------------------------------
__global__ __launch_bounds__(256) void zero_kernel(
    const int* __restrict__ latcnt,
    float* __restrict__ kh, float* __restrict__ kuv)
{
  int l = blockIdx.x, b = blockIdx.y;
  if (latcnt[l] <= SPLIT) return;
  size_t base = (size_t)b * PLANE + (size_t)l * NLON;
  for (int i = threadIdx.x; i < NLON; i += 256) kh[base + i] = 0.f;
  for (int i = threadIdx.x; i < 2 * NLON; i += 256) kuv[2 * base + i] = 0.f;
}

// ---------------------------------------------------------------------------
// Big-lat correlation: balanced grid (6 lon-chunks, NYSLOT, NB), block 256.
// Per-thread column; strides over worklist items (lat, 256-tap chunk);
// taps staged in LDS; atomicAdd partials into k-scratch.
// ---------------------------------------------------------------------------
__global__ __launch_bounds__(256) void big_kernel(
    const float* __restrict__ Xh, const float* __restrict__ Xuv,
    const int* __restrict__ latoff, const int* __restrict__ latcnt,
    const float4* __restrict__ tapw, const int2* __restrict__ tapm,
    const int2* __restrict__ work, const int* __restrict__ nbig,
    float* __restrict__ kh, float* __restrict__ kuv)
{
  __shared__ float4 sw[TCH];
  __shared__ int2   sm[TCH];

  int nbw = *nbig;
  int b = blockIdx.z;
  int tid = threadIdx.x;
  int n = blockIdx.x * 256 + tid;
  bool act = n < NLON;

  const float* __restrict__ xh  = Xh  + (size_t)b * PLANE;
  const float* __restrict__ xuv = Xuv + (size_t)b * PLANE * 2;

  for (int w = blockIdx.y; w < nbw; w += NYSLOT) {
    int2 it = work[w];
    int l = it.x;
    int t0 = latoff[l] + it.y * TCH;
    int tcnt = min(TCH, latcnt[l] - it.y * TCH);

    __syncthreads();                      // protect sw/sm reuse
    if (tid < tcnt) { sw[tid] = tapw[t0 + tid]; sm[tid] = tapm[t0 + tid]; }
    __syncthreads();

    if (act) {
      float ah = 0.f, au = 0.f, av = 0.f;
      #pragma unroll 4
      for (int t = 0; t < tcnt; ++t) {
        float4 wv = sw[t];
        int2   m  = sm[t];
        int nn = n + m.y;
        nn += (nn < 0) ? NLON : 0;
        nn -= (nn >= NLON) ? NLON : 0;
        int src = m.x + nn;
        float  hh = xh[src];
        float2 uv = *(const float2*)(xuv + 2 * (size_t)src);
        ah = fmaf(wv.z, uv.x, ah); ah = fmaf(wv.w, uv.y, ah);
        au = fmaf(wv.x, hh, au);
        av = fmaf(wv.y, hh, av);
      }
      size_t ih = (size_t)b * PLANE + (size_t)l * NLON + n;
      atomicAdd(&kh[ih], ah);
      atomicAdd(&kuv[2 * ih],     au);
      atomicAdd(&kuv[2 * ih + 1], av);
    }
  }
}

// ---------------------------------------------------------------------------
// Fused stage kernel, per-thread column.  Grid (6, NLAT, NB), block 256.
// Small lats: corr from LDS-staged taps.  Big lats: read k-scratch.
// Every active thread applies Coriolis + RK4 update + accumulator itself.
// blockIdx.y remapped so heavy (polar) lats are scheduled first.
// ---------------------------------------------------------------------------
__global__ __launch_bounds__(256) void stage_kernel(
    const float* __restrict__ Xh, const float* __restrict__ Xuv,
    const float* __restrict__ S0h, const float* __restrict__ S0uv,
    const float* __restrict__ fcor,
    const int* __restrict__ latoff, const int* __restrict__ latcnt,
    const float4* __restrict__ tapw, const int2* __restrict__ tapm,
    const float* __restrict__ kh_s, const float* __restrict__ kuv_s,
    float* __restrict__ Xn_h, float* __restrict__ Xn_uv,
    float* __restrict__ acc_h, float* __restrict__ acc_uv,
    float cdt, float wacc, int is_final)
{
  __shared__ float4 sw[SPLIT];
  __shared__ int2   sm[SPLIT];

  int y = blockIdx.y;                       // heavy-first lat remap
  int l = (y & 1) ? (NLAT - 1 - (y >> 1)) : (y >> 1);
  int b = blockIdx.z;
  int tid = threadIdx.x;
  int n = blockIdx.x * 256 + tid;
  bool act = n < NLON;

  int cnt = latcnt[l];
  int t0 = latoff[l];

  const float* __restrict__ xh  = Xh  + (size_t)b * PLANE;
  const float* __restrict__ xuv = Xuv + (size_t)b * PLANE * 2;

  float ah = 0.f, au = 0.f, av = 0.f;

  if (cnt <= SPLIT) {                      // block-uniform branch
    for (int t = tid; t < cnt; t += 256) { sw[t] = tapw[t0 + t]; sm[t] = tapm[t0 + t]; }
    __syncthreads();
    if (act) {
      #pragma unroll 4
      for (int t = 0; t < cnt; ++t) {
        float4 wv = sw[t];
        int2   m  = sm[t];
        int nn = n + m.y;
        nn += (nn < 0) ? NLON : 0;
        nn -= (nn >= NLON) ? NLON : 0;
        int src = m.x + nn;
        float  hh = xh[src];
        float2 uv = *(const float2*)(xuv + 2 * (size_t)src);
        ah = fmaf(wv.z, uv.x, ah); ah = fmaf(wv.w, uv.y, ah);
        au = fmaf(wv.x, hh, au);
        av = fmaf(wv.y, hh, av);
      }
    }
  } else if (act) {
    size_t ih = (size_t)b * PLANE + (size_t)l * NLON + n;
    ah = kh_s[ih];
    float2 kuv2 = *(const float2*)(kuv_s + 2 * ih);
    au = kuv2.x;
    av = kuv2.y;
  }

  if (act) {
    float f = fcor[l];
    float2 uvc = *(const float2*)(xuv + 2 * ((size_t)l * NLON + n));
    float kh = -ah;                  // dh = -H0 * corr
    float ku = -au - f * uvc.y;      // du - f*v
    float kv = -av + f * uvc.x;      // dv + f*u
    size_t ih  = (size_t)b * PLANE + (size_t)l * NLON + n;
    size_t iuv = ih * 2;
    if (!is_final) {
      Xn_h[ih] = fmaf(cdt, kh, S0h[ih]);
      float2 s0 = *(const float2*)(S0uv + iuv);
      float2 xo;
      xo.x = fmaf(cdt, ku, s0.x);
      xo.y = fmaf(cdt, kv, s0.y);
      *(float2*)(Xn_uv + iuv) = xo;
      acc_h[ih] = fmaf(wacc, kh, acc_h[ih]);
      float2 a0 = *(const float2*)(acc_uv + iuv);
      a0.x = fmaf(wacc, ku, a0.x);
      a0.y = fmaf(wacc, kv, a0.y);
      *(float2*)(acc_uv + iuv) = a0;
    } else {
      const float DT6 = DTSTEP / 6.0f;
      acc_h[ih] = fmaf(DT6, acc_h[ih] + kh, S0h[ih]);
      float2 s0 = *(const float2*)(S0uv + iuv);
      float2 a0 = *(const float2*)(acc_uv + iuv);
      a0.x = fmaf(DT6, a0.x + ku, s0.x);
      a0.y = fmaf(DT6, a0.y + kv, s0.y);
      *(float2*)(acc_uv + iuv) = a0;
    }
  }
}

// ---------------------------------------------------------------------------
extern "C" void kernel_launch(void* const* d_in, const int* in_sizes, int n_in,
                              void* d_out, int out_size, void* d_ws, size_t ws_size,
                              hipStream_t stream)
{
  const float* h0   = (const float*)d_in[0];
  const float* uv0  = (const float*)d_in[1];
  const float* Kgc  = (const float*)d_in[2];
  const float* Kgs  = (const float*)d_in[3];
  const float* Kdc  = (const float*)d_in[4];
  const float* Kds  = (const float*)d_in[5];
  const float* fcor = (const float*)d_in[6];

  char* ws = (char*)d_ws;
  size_t pos = 0;
  auto carve = [&](size_t bytes) -> void* {
    void* p = ws + pos;
    pos += (bytes + 255) & ~(size_t)255;
    return p;
  };

  int*   jlo_a  = (int*)carve(sizeof(int) * NROWS);
  int*   cnt_a  = (int*)carve(sizeof(int) * NROWS);
  int*   off_a  = (int*)carve(sizeof(int) * NROWS);
  int*   latoff = (int*)carve(sizeof(int) * NLAT);
  int*   latcnt = (int*)carve(sizeof(int) * NLAT);
  int2*  work   = (int2*)carve(sizeof(int2) * NWORK_CAP);
  int*   nbig   = (int*)carve(sizeof(int));
  float* Xa     = (float*)carve(sizeof(float) * 3 * (size_t)HVOL);
  float* Xb     = (float*)carve(sizeof(float) * 3 * (size_t)HVOL);
  float* kh     = (float*)carve(sizeof(float) * (size_t)HVOL);
  float* kuv    = (float*)carve(sizeof(float) * 2 * (size_t)HVOL);

  int tap_cap = 262144;   // ~4x expected total tap count (~65k)
  float4* tapw = (float4*)carve(sizeof(float4) * (size_t)tap_cap);
  int2*   tapm = (int2*)carve(sizeof(int2) * (size_t)tap_cap);

  float* Xa_h = Xa;  float* Xa_uv = Xa + HVOL;
  float* Xb_h = Xb;  float* Xb_uv = Xb + HVOL;
  float* acc_h  = (float*)d_out;          // [NB,1,NLAT,NLON]
  float* acc_uv = (float*)d_out + HVOL;   // [NB,1,NLAT,NLON,2]

  hipMemsetAsync(d_out, 0, sizeof(float) * (size_t)out_size, stream);

  support_kernel<<<NROWS, 64, 0, stream>>>(Kgc, Kgs, Kdc, Kds, jlo_a, cnt_a);
  scan_kernel<<<1, 256, 0, stream>>>(cnt_a, off_a, latoff, latcnt, work, nbig, tap_cap);
  fill_kernel<<<NROWS, 64, 0, stream>>>(Kgc, Kgs, Kdc, Kds, jlo_a, cnt_a, off_a,
                                        tapw, tapm, tap_cap);

  dim3 gz(NLAT, NB);
  dim3 gb(6, NYSLOT, NB);
  dim3 gs(6, NLAT, NB);

  struct Stage { const float *xh, *xuv; float *nh, *nuv; float cdt, wacc; int fin; };
  Stage st[4] = {
    { h0,   uv0,   Xa_h, Xa_uv, 0.5f * DTSTEP, 1.0f, 0 },
    { Xa_h, Xa_uv, Xb_h, Xb_uv, 0.5f * DTSTEP, 2.0f, 0 },
    { Xb_h, Xb_uv, Xa_h, Xa_uv, DTSTEP,        2.0f, 0 },
    { Xa_h, Xa_uv, Xb_h, Xb_uv, 0.0f,          0.0f, 1 },
  };

  for (int s = 0; s < 4; ++s) {
    zero_kernel<<<gz, 256, 0, stream>>>(latcnt, kh, kuv);
    big_kernel<<<gb, 256, 0, stream>>>(st[s].xh, st[s].xuv, latoff, latcnt,
                                       tapw, tapm, work, nbig, kh, kuv);
    stage_kernel<<<gs, 256, 0, stream>>>(st[s].xh, st[s].xuv, h0, uv0, fcor,
                                         latoff, latcnt, tapw, tapm, kh, kuv,
                                         st[s].nh, st[s].nuv, acc_h, acc_uv,
                                         st[s].cdt, st[s].wacc, st[s].fin);
  }
}